// Round 8
// baseline (129.042 us; speedup 1.0000x reference)
//
#include <hip/hip_runtime.h>

#define N_BINS 15
#define NREP 128    // one replica per (tid>>1): lanes sub=0,2,4,6 get private rows
#define RSTRIDE 17  // odd stride: 17*g mod 32 bijective -> conflict-free RMWs

typedef float f32x4 __attribute__((ext_vector_type(4)));

// One DPP butterfly step: max with a permuted copy (pure VALU, no LDS pipe).
template <int CTRL>
__device__ __forceinline__ unsigned dpp_umax(unsigned key) {
    unsigned other = (unsigned)__builtin_amdgcn_update_dpp(0, (int)key, CTRL, 0xF, 0xF, true);
    return key >= other ? key : other;
}

// 8-lane-group max: quad_perm[1,0,3,2], quad_perm[2,3,0,1], row_half_mirror.
// Result broadcast to all 8 lanes of the group.
__device__ __forceinline__ unsigned group8_umax(unsigned key) {
    key = dpp_umax<0xB1>(key);
    key = dpp_umax<0x4E>(key);
    key = dpp_umax<0x141>(key);
    return key;
}

// key = (fp32 bits & ~63) | (63 - col): positive floats compare as uints;
// ties on truncated value pick smallest col (jnp.argmax first-wins).
__device__ __forceinline__ unsigned pack_reduce(f32x4 v, unsigned colbase) {
    unsigned k0 = (__float_as_uint(v.x) & 0xFFFFFFC0u) | colbase;
    unsigned k1 = (__float_as_uint(v.y) & 0xFFFFFFC0u) | (colbase - 1u);
    unsigned k2 = (__float_as_uint(v.z) & 0xFFFFFFC0u) | (colbase - 2u);
    unsigned k3 = (__float_as_uint(v.w) & 0xFFFFFFC0u) | (colbase - 3u);
    unsigned a = k0 > k1 ? k0 : k1;
    unsigned b = k2 > k3 ? k2 : k3;
    return group8_umax(a > b ? a : b);
}

// ece = (1/n) * sum_b | sum_{rows in b} (conf - acc) |  (exact rewrite of the
// reference: safe==count when count>0; empty bins contribute 0). One RMW/row.
__device__ __forceinline__ void lane_update(unsigned key, int lab, float* rep) {
    const float best = __uint_as_float(key & 0xFFFFFFC0u);
    const int col = 63 - (int)(key & 63u);
    const float d = best - ((col == lab) ? 1.0f : 0.0f);
    if (best > 0.0f) {  // bin b covers (b/15,(b+1)/15]; conf==0 in no bin
        int b = (int)ceilf(best * 15.0f) - 1;
        b = b < 0 ? 0 : (b > N_BINS - 1 ? N_BINS - 1 : b);
        rep[b] += d;
    }
}

// ws layout: [0..14] per-bin sum of (conf-acc), ws[15] = completion counter.
__global__ __launch_bounds__(256) void ece_kernel(const float* __restrict__ sm,
                                                  const int* __restrict__ labels,
                                                  float* __restrict__ ws,
                                                  float* __restrict__ out,
                                                  int n, int rows_per_wave, int nblocks) {
    __shared__ float s_hist[NREP * RSTRIDE];
    for (int i = threadIdx.x; i < NREP * RSTRIDE; i += blockDim.x) s_hist[i] = 0.f;
    __syncthreads();

    const int lane = threadIdx.x & 63;
    const int grp = lane >> 3;   // 0..7: row within each 8-row load
    const int sub = lane & 7;    // 0..7: float4 within the row
    const int wave_id = (blockIdx.x * blockDim.x + threadIdx.x) >> 6;

    float* rep = s_hist + (threadIdx.x >> 1) * RSTRIDE;  // private per even lane
    const unsigned colbase = 63u - (unsigned)(sub * 4);
    const int laboff = 8 * (sub >> 1) + grp;  // the one label this lane updates

    const int n32 = n & ~31;
    const int row_begin = wave_id * rows_per_wave;
    int row_end = row_begin + rows_per_wave;
    if (row_end > n32) row_end = n32;

    // Software pipeline: the LDS RMW for iteration i runs AFTER iteration
    // i+1's global loads are issued, so ds latency hides under VMEM flight.
    int r0 = row_begin;
    if (r0 < row_end) {
        const f32x4* base = reinterpret_cast<const f32x4*>(sm + (size_t)r0 * 32);
        f32x4 v0 = base[lane], v1 = base[64 + lane], v2 = base[128 + lane], v3 = base[192 + lane];
        int lab_prev = labels[r0 + laboff];
        unsigned k0 = pack_reduce(v0, colbase);
        unsigned k1 = pack_reduce(v1, colbase);
        unsigned k2 = pack_reduce(v2, colbase);
        unsigned k3 = pack_reduce(v3, colbase);
        // lane sub=0/1 -> k0, 2/3 -> k1, 4/5 -> k2, 6/7 -> k3 (even lanes update)
        unsigned key_prev = sub < 2 ? k0 : sub < 4 ? k1 : sub < 6 ? k2 : k3;

        for (r0 += 32; r0 < row_end; r0 += 32) {
            const f32x4* b2 = reinterpret_cast<const f32x4*>(sm + (size_t)r0 * 32);
            f32x4 w0 = b2[lane], w1 = b2[64 + lane], w2 = b2[128 + lane], w3 = b2[192 + lane];
            int lab_cur = labels[r0 + laboff];
            if ((sub & 1) == 0) lane_update(key_prev, lab_prev, rep);  // overlaps loads
            unsigned c0 = pack_reduce(w0, colbase);
            unsigned c1 = pack_reduce(w1, colbase);
            unsigned c2 = pack_reduce(w2, colbase);
            unsigned c3 = pack_reduce(w3, colbase);
            key_prev = sub < 2 ? c0 : sub < 4 ? c1 : sub < 6 ? c2 : c3;
            lab_prev = lab_cur;
        }
        if ((sub & 1) == 0) lane_update(key_prev, lab_prev, rep);
    }

    __syncthreads();
    // fold 128 replicas -> one global atomic per bin per block
    if (threadIdx.x < N_BINS) {
        float s = 0.f;
        #pragma unroll
        for (int r = 0; r < NREP; ++r) s += s_hist[r * RSTRIDE + threadIdx.x];
        atomicAdd(&ws[threadIdx.x], s);
    }

    // tail rows [n32, n) (empty for n=2M): block 0, exact scalar path
    if (blockIdx.x == 0 && threadIdx.x < (n - n32)) {
        const int row = n32 + threadIdx.x;
        const float* rp = sm + (size_t)row * 32;
        float best = rp[0];
        int bi = 0;
        for (int c = 1; c < 32; ++c) {
            float x = rp[c];
            if (x > best) { best = x; bi = c; }
        }
        const float d = best - ((bi == labels[row]) ? 1.0f : 0.0f);
        if (best > 0.0f) {
            int b = (int)ceilf(best * 15.0f) - 1;
            b = b < 0 ? 0 : (b > N_BINS - 1 ? N_BINS - 1 : b);
            atomicAdd(&ws[b], d);
        }
    }

    // fused finalize: last block to arrive folds ws -> out (threadfence ticket).
    // Each block increments only after ITS contributions are fenced, so the
    // last incrementer observes all adds (device-scope; XCD-safe per G16).
    __syncthreads();
    if (threadIdx.x == 0) {
        __threadfence();
        unsigned old = atomicAdd(reinterpret_cast<unsigned*>(ws + N_BINS), 1u);
        if (old == (unsigned)(nblocks - 1)) {
            float ece = 0.f;
            #pragma unroll
            for (int b = 0; b < N_BINS; ++b) ece += fabsf(atomicAdd(&ws[b], 0.0f));
            out[0] = ece / (float)n;
        }
    }
}

extern "C" void kernel_launch(void* const* d_in, const int* in_sizes, int n_in,
                              void* d_out, int out_size, void* d_ws, size_t ws_size,
                              hipStream_t stream) {
    const float* sm = (const float*)d_in[0];
    const int* labels = (const int*)d_in[1];  // int64 in reference -> int32 in harness
    float* ws = (float*)d_ws;
    float* out = (float*)d_out;
    const int n = in_sizes[1];  // 2,000,000 rows

    // ws is poisoned (0xAA) once and never re-poisoned: zero bins+counter EVERY call.
    (void)hipMemsetAsync(ws, 0, (N_BINS + 1) * sizeof(float), stream);

    const int block = 256;
    const int grid = 2048;                     // 8192 waves
    const int waves = grid * (block / 64);
    const int n32 = n & ~31;
    const int chunks = (n32 / 32 + waves - 1) / waves;
    const int rows_per_wave = chunks * 32;     // n=2M -> 256 rows (32 KB) per wave

    ece_kernel<<<grid, block, 0, stream>>>(sm, labels, ws, out, n, rows_per_wave, grid);
}

// Round 9
// 63.216 us; speedup vs baseline: 2.0413x; 2.0413x over previous
//
#include <hip/hip_runtime.h>

#define N_BINS 15
#define NREP 64     // one replica per (tid>>2): leader lanes sub=0 and sub=4
#define RSTRIDE 17  // odd stride: consecutive replicas -> distinct banks

typedef float f32x4 __attribute__((ext_vector_type(4)));

// One DPP butterfly step: max with a permuted copy (pure VALU, no LDS pipe).
template <int CTRL>
__device__ __forceinline__ unsigned dpp_umax(unsigned key) {
    unsigned other = (unsigned)__builtin_amdgcn_update_dpp(0, (int)key, CTRL, 0xF, 0xF, true);
    return key >= other ? key : other;
}

// 8-lane-group max: quad_perm[1,0,3,2], quad_perm[2,3,0,1], row_half_mirror.
// Result broadcast to all 8 lanes of the group.
__device__ __forceinline__ unsigned group8_umax(unsigned key) {
    key = dpp_umax<0xB1>(key);
    key = dpp_umax<0x4E>(key);
    key = dpp_umax<0x141>(key);
    return key;
}

// key = (fp32 bits & ~63) | (63 - col): positive floats compare as uints;
// ties on truncated value pick smallest col (jnp.argmax first-wins).
__device__ __forceinline__ unsigned pack_reduce(f32x4 v, unsigned colbase) {
    unsigned k0 = (__float_as_uint(v.x) & 0xFFFFFFC0u) | colbase;
    unsigned k1 = (__float_as_uint(v.y) & 0xFFFFFFC0u) | (colbase - 1u);
    unsigned k2 = (__float_as_uint(v.z) & 0xFFFFFFC0u) | (colbase - 2u);
    unsigned k3 = (__float_as_uint(v.w) & 0xFFFFFFC0u) | (colbase - 3u);
    unsigned a = k0 > k1 ? k0 : k1;
    unsigned b = k2 > k3 ? k2 : k3;
    return group8_umax(a > b ? a : b);
}

// ece = (1/n) * sum_b | sum_{rows in b} (conf - acc) |  (exact rewrite of the
// reference: safe==count when count>0; empty bins contribute 0). One RMW/row.
__device__ __forceinline__ void lane_update(unsigned key, int lab, float* rep) {
    const float best = __uint_as_float(key & 0xFFFFFFC0u);
    const int col = 63 - (int)(key & 63u);
    const float d = best - ((col == lab) ? 1.0f : 0.0f);
    if (best > 0.0f) {  // bin b covers (b/15,(b+1)/15]; conf==0 in no bin
        int b = (int)ceilf(best * 15.0f) - 1;
        b = b < 0 ? 0 : (b > N_BINS - 1 ? N_BINS - 1 : b);
        rep[b] += d;
    }
}

// ws layout: [0..14] = per-bin sum of (conf - acc)
__global__ __launch_bounds__(256) void ece_bin_kernel(const float* __restrict__ sm,
                                                      const int* __restrict__ labels,
                                                      float* __restrict__ ws, int n,
                                                      int rows_per_wave) {
    __shared__ float s_hist[NREP * RSTRIDE];
    for (int i = threadIdx.x; i < NREP * RSTRIDE; i += blockDim.x) s_hist[i] = 0.f;
    __syncthreads();

    const int lane = threadIdx.x & 63;
    const int grp = lane >> 3;   // 0..7: row within each 8-row load
    const int sub = lane & 7;    // 0..7: float4 within the row
    const int wave_id = (blockIdx.x * blockDim.x + threadIdx.x) >> 6;

    float* rep = s_hist + (threadIdx.x >> 2) * RSTRIDE;  // private per leader lane
    const unsigned colbase = 63u - (unsigned)(sub * 4);

    // contiguous region per wave: sequential stream, 8 KB (64 rows) in flight/iter
    const int n64 = n & ~63;
    const int row_begin = wave_id * rows_per_wave;
    int row_end = row_begin + rows_per_wave;
    if (row_end > n64) row_end = n64;

    for (int r0 = row_begin; r0 < row_end; r0 += 64) {
        const f32x4* base = reinterpret_cast<const f32x4*>(sm + (size_t)r0 * 32);
        const f32x4 v0 = base[lane];          // rows r0    ..+7
        const f32x4 v1 = base[64 + lane];     // rows r0+8  ..+15
        const f32x4 v2 = base[128 + lane];    // rows r0+16 ..+23
        const f32x4 v3 = base[192 + lane];    // rows r0+24 ..+31
        const f32x4 v4 = base[256 + lane];    // rows r0+32 ..+39
        const f32x4 v5 = base[320 + lane];    // rows r0+40 ..+47
        const f32x4 v6 = base[384 + lane];    // rows r0+48 ..+55
        const f32x4 v7 = base[448 + lane];    // rows r0+56 ..+63
        const int lab0 = labels[r0 + grp];    // unconditional broadcast loads
        const int lab1 = labels[r0 + 8 + grp];
        const int lab2 = labels[r0 + 16 + grp];
        const int lab3 = labels[r0 + 24 + grp];
        const int lab4 = labels[r0 + 32 + grp];
        const int lab5 = labels[r0 + 40 + grp];
        const int lab6 = labels[r0 + 48 + grp];
        const int lab7 = labels[r0 + 56 + grp];
        const unsigned k0 = pack_reduce(v0, colbase);
        const unsigned k1 = pack_reduce(v1, colbase);
        const unsigned k2 = pack_reduce(v2, colbase);
        const unsigned k3 = pack_reduce(v3, colbase);
        const unsigned k4 = pack_reduce(v4, colbase);
        const unsigned k5 = pack_reduce(v5, colbase);
        const unsigned k6 = pack_reduce(v6, colbase);
        const unsigned k7 = pack_reduce(v7, colbase);
        // TWO leader lanes per group (sub 0 and 4) in ONE masked body:
        // chain stays 4 RMWs; both leader sets run in the same instructions.
        if ((sub & 3) == 0) {
            const bool hi = (sub != 0);
            lane_update(hi ? k4 : k0, hi ? lab4 : lab0, rep);
            lane_update(hi ? k5 : k1, hi ? lab5 : lab1, rep);
            lane_update(hi ? k6 : k2, hi ? lab6 : lab2, rep);
            lane_update(hi ? k7 : k3, hi ? lab7 : lab3, rep);
        }
    }

    __syncthreads();
    // fold 64 replicas -> one global atomic per bin per block
    if (threadIdx.x < N_BINS) {
        float s = 0.f;
        #pragma unroll
        for (int r = 0; r < NREP; ++r) s += s_hist[r * RSTRIDE + threadIdx.x];
        atomicAdd(&ws[threadIdx.x], s);
    }

    // tail rows [n64, n) (empty for n=2M): block 0, exact scalar path
    if (blockIdx.x == 0 && threadIdx.x < (n - n64)) {
        const int row = n64 + threadIdx.x;
        const float* rp = sm + (size_t)row * 32;
        float best = rp[0];
        int bi = 0;
        for (int c = 1; c < 32; ++c) {
            float x = rp[c];
            if (x > best) { best = x; bi = c; }
        }
        const float d = best - ((bi == labels[row]) ? 1.0f : 0.0f);
        if (best > 0.0f) {
            int b = (int)ceilf(best * 15.0f) - 1;
            b = b < 0 ? 0 : (b > N_BINS - 1 ? N_BINS - 1 : b);
            atomicAdd(&ws[b], d);
        }
    }
}

__global__ void ece_final_kernel(const float* __restrict__ ws, float* __restrict__ out, int n) {
    if (threadIdx.x == 0 && blockIdx.x == 0) {
        float ece = 0.f;
        #pragma unroll
        for (int b = 0; b < N_BINS; ++b) ece += fabsf(ws[b]);
        out[0] = ece / (float)n;
    }
}

extern "C" void kernel_launch(void* const* d_in, const int* in_sizes, int n_in,
                              void* d_out, int out_size, void* d_ws, size_t ws_size,
                              hipStream_t stream) {
    const float* sm = (const float*)d_in[0];
    const int* labels = (const int*)d_in[1];  // int64 in reference -> int32 in harness
    float* ws = (float*)d_ws;
    float* out = (float*)d_out;
    const int n = in_sizes[1];  // 2,000,000 rows

    // ws is poisoned (0xAA) once and never re-poisoned: zero it EVERY call.
    (void)hipMemsetAsync(ws, 0, N_BINS * sizeof(float), stream);

    const int block = 256;
    const int grid = 2048;                     // 8192 waves
    const int waves = grid * (block / 64);
    const int n64 = n & ~63;
    const int chunks = (n64 / 64 + waves - 1) / waves;
    const int rows_per_wave = chunks * 64;     // n=2M -> 256 rows (32 KB) per wave

    ece_bin_kernel<<<grid, block, 0, stream>>>(sm, labels, ws, n, rows_per_wave);
    ece_final_kernel<<<1, 64, 0, stream>>>(ws, out, n);
}